// Round 14
// baseline (2218.475 us; speedup 1.0000x reference)
//
#include <hip/hip_runtime.h>
#include <hip/hip_fp16.h>
#include <cstddef>

#define TT 2048   // time steps
#define BB 256    // batch
#define DD 32     // input dim
#define HH 64     // hidden
#define GG 256    // 4*H
#define RING 8
#define RMASK 7

__device__ __forceinline__ float sigmf(float v)  { return 1.0f / (1.0f + __expf(-v)); }
__device__ __forceinline__ float tanhf_(float v) { return 2.0f / (1.0f + __expf(-2.0f * v)) - 1.0f; }
__device__ __forceinline__ __half2 f_as_h2(float f) { union { float f; __half2 h; } c; c.f = f; return c.h; }
__device__ __forceinline__ __half2 u_as_h2(unsigned v) { union { unsigned u; __half2 h; } c; c.u = v; return c.h; }

// ---- flag handshake (per-CU LDS is coherent; lgkmcnt(0) orders data->flag) ----
__device__ __forceinline__ void spin_ge(volatile int* f, int v) {
    while (*f < v) {}
    asm volatile("" ::: "memory");   // no memory op crosses the spin
}
__device__ __forceinline__ void set_flag(volatile int* f, int v, int lane) {
    asm volatile("s_waitcnt lgkmcnt(0)" ::: "memory");  // my LDS ops done/visible
    if (lane == 0) *f = v;
}

// read 64 halfs (one h vector) from a ring slot into 32 half2 (broadcast b128s)
__device__ __forceinline__ void read_h64(const __half (*ring)[HH], int slot, __half2* hh) {
    const float4* hp = (const float4*)ring[slot];
    #pragma unroll
    for (int j = 0; j < 8; ++j) {
        float4 r = hp[j];
        hh[4*j+0] = f_as_h2(r.x); hh[4*j+1] = f_as_h2(r.y);
        hh[4*j+2] = f_as_h2(r.z); hh[4*j+3] = f_as_h2(r.w);
    }
}
// 4-gate dot over K=64 (all in-lane; 2 indep chains per gate)
__device__ __forceinline__ void dot4x64(const __half2 w[4][32], const __half2* hh, float* zg) {
    #pragma unroll
    for (int g = 0; g < 4; ++g) {
        __half2 s0 = __float2half2_rn(0.f), s1 = s0;
        #pragma unroll
        for (int j = 0; j < 16; ++j) s0 = __hfma2(w[g][j], hh[j], s0);
        #pragma unroll
        for (int j = 16; j < 32; ++j) s1 = __hfma2(w[g][j], hh[j], s1);
        __half2 s = __hadd2(s0, s1);
        zg[g] = __low2float(s) + __high2float(s);
    }
}
__device__ __forceinline__ void load_w(const float* M, int u, __half2 w[4][32]) {
    #pragma unroll
    for (int g = 0; g < 4; ++g) {
        const int col = g * HH + u;
        #pragma unroll
        for (int j = 0; j < 32; ++j)
            w[g][j] = __floats2half2_rn(M[(2*j) * GG + col], M[(2*j+1) * GG + col]);
    }
}

// ---------------- pre-kernel (R13-proven): zx[(b*TT+t)*256 + u*4+g] = x·W1 + b1, f16 ----------------
__global__ __launch_bounds__(256)
void zx_pre(const float* __restrict__ x, const float* __restrict__ W1,
            const float* __restrict__ b1, __half* __restrict__ zx)
{
    const int bb = blockIdx.x, tb = blockIdx.y, zr = threadIdx.x;  // zr = u*4+g
    __shared__ float xs[8][DD];
    const float* xb = x + ((size_t)bb * TT + (size_t)tb * 8) * DD;
    xs[zr >> 5][zr & 31] = xb[zr];
    __syncthreads();

    const int u = zr >> 2, g = zr & 3;
    const int colW = g * HH + u;
    float wcol[DD];
    #pragma unroll
    for (int d = 0; d < DD; ++d) wcol[d] = W1[d * GG + colW];
    const float bias = b1[colW];

    __half* zb = zx + ((size_t)bb * TT + (size_t)tb * 8) * 256 + zr;
    #pragma unroll
    for (int r8 = 0; r8 < 8; ++r8) {
        float z0 = bias, z1 = 0.f, z2 = 0.f, z3 = 0.f;
        #pragma unroll
        for (int d = 0; d < DD; d += 4) {
            z0 += xs[r8][d+0] * wcol[d+0];
            z1 += xs[r8][d+1] * wcol[d+1];
            z2 += xs[r8][d+2] * wcol[d+2];
            z3 += xs[r8][d+3] * wcol[d+3];
        }
        zb[(size_t)r8 * 256] = __float2half((z0 + z1) + (z2 + z3));
    }
}

// ---------------- recurrence: async 4-stage dataflow, ZERO per-step barriers ----------------
// One block per batch row; 256 threads = 4 waves = 4 pipeline stages (1/SIMD).
// Lane = unit. Rings (depth 8) + volatile flags replace lockstep barriers:
//   W0: L1 recurrence  (self-loop on h1ring; zx from global)      -> flag1
//   W1: v2 = W2*h1(n)  (spins flag1; v2ring)                      -> flag2, c1flag
//   W2: L2 recurrence  (self-loop on h2ring; spins flag2)         -> flag3, c2flag
//   W3: out projection (spins flag3)                              -> c3flag
// Wall/step = max(stage) since stages run concurrently on different SIMDs;
// the recurrence cycles are the two INTRA-WAVE self-loops (~550-650 cyc).
__global__ __launch_bounds__(256, 1)
void dlstm_rec(const __half* __restrict__ zx,
               const float* __restrict__ U1, const float* __restrict__ W2,
               const float* __restrict__ U2, const float* __restrict__ b2,
               const float* __restrict__ Wd, const float* __restrict__ bd,
               float* __restrict__ out)
{
    const int tid = threadIdx.x, b = blockIdx.x;
    const int wid = tid >> 6, u = tid & 63;

    __shared__ __align__(16) __half h1ring[RING][HH];
    __shared__ __align__(16) __half h2ring[RING][HH];
    __shared__ __align__(16) float v2ring[RING][HH][4];
    __shared__ int flag1, c1flag, flag2, c2flag, flag3, c3flag;

    for (int i = tid; i < RING * HH; i += 256) {
        h1ring[i >> 6][i & 63] = __float2half(0.f);   // h(-1..-8) = 0
        h2ring[i >> 6][i & 63] = __float2half(0.f);
    }
    if (tid == 0) { flag1 = 0; c1flag = 0; flag2 = 0; c2flag = 0; flag3 = 0; c3flag = 0; }
    __syncthreads();   // the ONLY block-wide barrier

    if (wid == 0) {
        // ---- stage 0: layer-1 recurrence ----
        __half2 u1w[4][32];
        load_w(U1, u, u1w);
        const __half* zp = zx + (size_t)b * TT * 256 + u * 4;
        uint2 zc = *(const uint2*)zp;      // zx(0), bias folded
        float c1 = 0.f;

        for (int n = 0; n < TT; ++n) {
            const size_t tn = (n + 1 < TT) ? (size_t)(n + 1) : (size_t)n;
            uint2 zn = *(const uint2*)(zp + tn * 256);   // prefetch, in flight all step

            spin_ge(&c1flag, n - (RING - 1));            // WAR: slot n&7 free?
            __half2 hh[32];
            read_h64(h1ring, (n - 1) & RMASK, hh);       // h1(n-1), own-wave sync
            float zg[4];
            dot4x64(u1w, hh, zg);
            __half2 zl = u_as_h2(zc.x), zh = u_as_h2(zc.y);
            zg[0] += __low2float(zl); zg[1] += __high2float(zl);
            zg[2] += __low2float(zh); zg[3] += __high2float(zh);
            float gi = sigmf(zg[0]), gf = sigmf(zg[1]);
            float gc = tanhf_(zg[2]), go = sigmf(zg[3]);
            c1 = gf * c1 + gi * gc;
            float h1n = go * tanhf_(c1);
            h1ring[n & RMASK][u] = __float2half(h1n);
            set_flag(&flag1, n + 1, u);
            zc = zn;
        }
    } else if (wid == 1) {
        // ---- stage 1: v2(n) = W2 · h1(n) ----
        __half2 w2w[4][32];
        load_w(W2, u, w2w);

        for (int n = 0; n < TT; ++n) {
            spin_ge(&flag1, n + 1);                      // h1(n) ready
            __half2 hh[32];
            read_h64(h1ring, n & RMASK, hh);
            float zg[4];
            dot4x64(w2w, hh, zg);
            spin_ge(&c2flag, n - (RING - 1));            // WAR: v2 slot free?
            float4 vv; vv.x = zg[0]; vv.y = zg[1]; vv.z = zg[2]; vv.w = zg[3];
            *(float4*)&v2ring[n & RMASK][u][0] = vv;
            set_flag(&flag2, n + 1, u);                  // v2(n) ready (lgkmcnt inside)
            set_flag(&c1flag, n + 1, u);                 // h1(n) consumed
        }
    } else if (wid == 2) {
        // ---- stage 2: layer-2 recurrence ----
        __half2 u2w[4][32];
        load_w(U2, u, u2w);
        float bz[4];
        #pragma unroll
        for (int g = 0; g < 4; ++g) bz[g] = b2[g * HH + u];
        float c2 = 0.f;

        for (int n = 0; n < TT; ++n) {
            spin_ge(&c3flag, n - (RING - 1));            // WAR: h2 slot free?
            __half2 hh2[32];
            read_h64(h2ring, (n - 1) & RMASK, hh2);      // h2(n-1), own-wave sync
            float zg[4];
            dot4x64(u2w, hh2, zg);                       // U2 part first: hides flag2 poll
            spin_ge(&flag2, n + 1);                      // v2(n) ready
            float4 vv = *(const float4*)&v2ring[n & RMASK][u][0];
            set_flag(&c2flag, n + 1, u);                 // v2(n) consumed (lgkmcnt waits read)
            float z0 = zg[0] + vv.x + bz[0], z1 = zg[1] + vv.y + bz[1];
            float z2 = zg[2] + vv.z + bz[2], z3 = zg[3] + vv.w + bz[3];
            float gi = sigmf(z0), gf = sigmf(z1);
            float gc = tanhf_(z2), go = sigmf(z3);
            c2 = gf * c2 + gi * gc;
            float h2n = go * tanhf_(c2);
            h2ring[n & RMASK][u] = __float2half(h2n);
            set_flag(&flag3, n + 1, u);
        }
    } else {
        // ---- stage 3: output projection ----
        __half2 wdw[32];
        #pragma unroll
        for (int j = 0; j < 32; ++j) wdw[j] = __floats2half2_rn(Wd[2*j], Wd[2*j+1]);
        const float bd0 = bd[0];
        float* outb = out + (size_t)b * TT;

        for (int n = 0; n < TT; ++n) {
            spin_ge(&flag3, n + 1);                      // h2(n) ready
            __half2 hh2[32];
            read_h64(h2ring, n & RMASK, hh2);
            __half2 pa = __float2half2_rn(0.f), pb = pa;
            #pragma unroll
            for (int j = 0; j < 16; ++j) pa = __hfma2(wdw[j], hh2[j], pa);
            #pragma unroll
            for (int j = 16; j < 32; ++j) pb = __hfma2(wdw[j], hh2[j], pb);
            __half2 ps = __hadd2(pa, pb);
            float v = __low2float(ps) + __high2float(ps);
            set_flag(&c3flag, n + 1, u);                 // h2(n) consumed
            if (u == 0) outb[n] = sigmf(v + bd0);
        }
    }
}

// ---------------- fallback: R8 kernel (1921us proven) if ws too small ----------------
__global__ __launch_bounds__(512, 2)
void dlstm_fb(const float* __restrict__ x,
              const float* __restrict__ W1, const float* __restrict__ U1,
              const float* __restrict__ b1,
              const float* __restrict__ W2, const float* __restrict__ U2,
              const float* __restrict__ b2,
              const float* __restrict__ Wd, const float* __restrict__ bd,
              float* __restrict__ out)
{
    const int tid = threadIdx.x, b = blockIdx.x;
    const int wid = tid >> 6, l = tid & 63;
    const int kq = l >> 4, ul = l & 15;

    __shared__ __align__(16) __half h1b[2][HH];
    __shared__ __align__(16) __half h2b[2][HH];
    __shared__ float pbuf[2][4];

    if (tid < HH) {
        h1b[0][tid] = __float2half(0.f); h1b[1][tid] = __float2half(0.f);
        h2b[0][tid] = __float2half(0.f); h2b[1][tid] = __float2half(0.f);
    }
    if (tid < 8) pbuf[tid >> 2][tid & 3] = 0.f;
    __syncthreads();

    if (wid < 4) {
        const int u = (wid << 4) + ul;
        __half2 u1p[4][8];
        #pragma unroll
        for (int gp = 0; gp < 4; ++gp)
            #pragma unroll
            for (int j = 0; j < 8; ++j)
                u1p[gp][j] = __floats2half2_rn(U1[(kq*16 + 2*j) * GG + gp*HH + u],
                                               U1[(kq*16 + 2*j + 1) * GG + gp*HH + u]);
        __half2 w1p[4][4];
        #pragma unroll
        for (int gp = 0; gp < 4; ++gp)
            #pragma unroll
            for (int j = 0; j < 4; ++j)
                w1p[gp][j] = __floats2half2_rn(W1[(kq*8 + 2*j) * GG + gp*HH + u],
                                               W1[(kq*8 + 2*j + 1) * GG + gp*HH + u]);
        const float b1k = b1[kq * HH + u];
        const float bd0 = bd[0];
        float c1 = 0.f;
        const float* xr = x + (size_t)b * TT * DD + kq * 8;
        float4 xa = *(const float4*)(xr);
        float4 xb = *(const float4*)(xr + 4);

        for (int n = 0; n < TT + 2; ++n) {
            const int p = n & 1;
            if (n < TT) {
                const size_t tn = (n + 1 < TT) ? (size_t)(n + 1) : (size_t)n;
                float4 na = *(const float4*)(xr + tn * DD);
                float4 nb = *(const float4*)(xr + tn * DD + 4);
                __half2 xx[4];
                xx[0] = __floats2half2_rn(xa.x, xa.y);
                xx[1] = __floats2half2_rn(xa.z, xa.w);
                xx[2] = __floats2half2_rn(xb.x, xb.y);
                xx[3] = __floats2half2_rn(xb.z, xb.w);
                const __half2* hp = (const __half2*)&h1b[p][kq * 16];
                __half2 hh[8];
                #pragma unroll
                for (int j = 0; j < 8; ++j) hh[j] = hp[j];
                float ag[4];
                #pragma unroll
                for (int gp = 0; gp < 4; ++gp) {
                    __half2 s = __float2half2_rn(0.f);
                    #pragma unroll
                    for (int j = 0; j < 8; ++j) s = __hfma2(u1p[gp][j], hh[j], s);
                    #pragma unroll
                    for (int j = 0; j < 4; ++j) s = __hfma2(w1p[gp][j], xx[j], s);
                    ag[gp] = __low2float(s) + __high2float(s);
                }
                float t1 = (kq & 1) ? ag[0] : ag[1];
                float t2 = (kq & 1) ? ag[2] : ag[3];
                float r1 = __shfl_xor(t1, 16, 64);
                float r2 = __shfl_xor(t2, 16, 64);
                float m1 = (kq & 1) ? ag[1] : ag[0];
                float m2 = (kq & 1) ? ag[3] : ag[2];
                float s1 = m1 + r1, s2 = m2 + r2;
                float t3 = (kq < 2) ? s2 : s1;
                float r3 = __shfl_xor(t3, 32, 64);
                float mine = (kq < 2) ? s1 : s2;
                float z = mine + r3 + b1k;
                float a = (kq == 2) ? tanhf_(z) : sigmf(z);
                float g16 = __shfl_xor(a, 16, 64);
                float g32 = __shfl_xor(a, 32, 64);
                float g48 = __shfl_xor(g16, 32, 64);
                c1 = g16 * c1 + a * g32;
                float h = g48 * tanhf_(c1);
                if (kq == 0) h1b[p ^ 1][u] = __float2half(h);
                xa = na; xb = nb;
            }
            if (tid == 0 && n >= 2) {
                float s = pbuf[p][0] + pbuf[p][1] + pbuf[p][2] + pbuf[p][3];
                out[(size_t)b * TT + (n - 2)] = sigmf(s + bd0);
            }
            __syncthreads();
        }
    } else {
        const int w2i = wid - 4;
        const int u = (w2i << 4) + ul;
        __half2 w2p[4][8], u2p[4][8];
        #pragma unroll
        for (int gp = 0; gp < 4; ++gp)
            #pragma unroll
            for (int j = 0; j < 8; ++j) {
                w2p[gp][j] = __floats2half2_rn(W2[(kq*16 + 2*j) * GG + gp*HH + u],
                                               W2[(kq*16 + 2*j + 1) * GG + gp*HH + u]);
                u2p[gp][j] = __floats2half2_rn(U2[(kq*16 + 2*j) * GG + gp*HH + u],
                                               U2[(kq*16 + 2*j + 1) * GG + gp*HH + u]);
            }
        const float b2k = b2[kq * HH + u];
        const float wdu = Wd[u];
        float c2 = 0.f;

        for (int n = 0; n < TT + 2; ++n) {
            const int p = n & 1;
            if (n >= 1 && n <= TT) {
                const __half2* h1p = (const __half2*)&h1b[p][kq * 16];
                const __half2* h2p = (const __half2*)&h2b[p][kq * 16];
                __half2 hh1[8], hh2[8];
                #pragma unroll
                for (int j = 0; j < 8; ++j) { hh1[j] = h1p[j]; hh2[j] = h2p[j]; }
                float ag[4];
                #pragma unroll
                for (int gp = 0; gp < 4; ++gp) {
                    __half2 s = __float2half2_rn(0.f);
                    #pragma unroll
                    for (int j = 0; j < 8; ++j) s = __hfma2(w2p[gp][j], hh1[j], s);
                    #pragma unroll
                    for (int j = 0; j < 8; ++j) s = __hfma2(u2p[gp][j], hh2[j], s);
                    ag[gp] = __low2float(s) + __high2float(s);
                }
                float t1 = (kq & 1) ? ag[0] : ag[1];
                float t2 = (kq & 1) ? ag[2] : ag[3];
                float r1 = __shfl_xor(t1, 16, 64);
                float r2 = __shfl_xor(t2, 16, 64);
                float m1 = (kq & 1) ? ag[1] : ag[0];
                float m2 = (kq & 1) ? ag[3] : ag[2];
                float s1 = m1 + r1, s2 = m2 + r2;
                float t3 = (kq < 2) ? s2 : s1;
                float r3 = __shfl_xor(t3, 32, 64);
                float mine = (kq < 2) ? s1 : s2;
                float z = mine + r3 + b2k;
                float a = (kq == 2) ? tanhf_(z) : sigmf(z);
                float g16 = __shfl_xor(a, 16, 64);
                float g32 = __shfl_xor(a, 32, 64);
                float g48 = __shfl_xor(g16, 32, 64);
                c2 = g16 * c2 + a * g32;
                float h = g48 * tanhf_(c2);
                if (kq == 0) h2b[p ^ 1][u] = __float2half(h);
                float v = (kq == 0) ? h * wdu : 0.f;
                v += __shfl_xor(v, 1, 64);
                v += __shfl_xor(v, 2, 64);
                v += __shfl_xor(v, 4, 64);
                v += __shfl_xor(v, 8, 64);
                if (l == 0) pbuf[p ^ 1][w2i] = v;
            }
            __syncthreads();
        }
    }
}

extern "C" void kernel_launch(void* const* d_in, const int* in_sizes, int n_in,
                              void* d_out, int out_size, void* d_ws, size_t ws_size,
                              hipStream_t stream) {
    const float* x  = (const float*)d_in[0];
    const float* W1 = (const float*)d_in[1];
    const float* U1 = (const float*)d_in[2];
    const float* b1 = (const float*)d_in[3];
    const float* W2 = (const float*)d_in[4];
    const float* U2 = (const float*)d_in[5];
    const float* b2 = (const float*)d_in[6];
    const float* Wd = (const float*)d_in[7];
    const float* bd = (const float*)d_in[8];
    float* out = (float*)d_out;

    const size_t need_f16 = (size_t)BB * TT * GG * sizeof(__half);  // 268 MB (proven fits)

    if (ws_size >= need_f16) {
        __half* zxw = (__half*)d_ws;
        zx_pre<<<dim3(BB, TT / 8), dim3(256), 0, stream>>>(x, W1, b1, zxw);
        dlstm_rec<<<dim3(BB), dim3(256), 0, stream>>>(zxw, U1, W2, U2, b2, Wd, bd, out);
    } else {
        dlstm_fb<<<dim3(BB), dim3(512), 0, stream>>>(x, W1, U1, b1, W2, U2, b2, Wd, bd, out);
    }
}

// Round 15
// 1751.379 us; speedup vs baseline: 1.2667x; 1.2667x over previous
//
#include <hip/hip_runtime.h>
#include <hip/hip_fp16.h>
#include <cstddef>

#define TT 2048   // time steps
#define BB 256    // batch
#define DD 32     // input dim
#define HH 64     // hidden
#define GG 256    // 4*H

// 7th-order rational tanh (cuDNN-style): err ~1e-7 for |x|<4.97, clamped
// beyond (|err|<1.4e-4). Chain ~40cy (2 parallel Horner + v_rcp) vs ~100cy
// for the exp+rcp path -- this is on the recurrence-critical path 2x/layer.
__device__ __forceinline__ float tanh_rat(float x) {
    x = fminf(fmaxf(x, -4.97f), 4.97f);
    float x2 = x * x;
    float p = x * fmaf(x2, fmaf(x2, x2 + 378.0f, 17325.0f), 135135.0f);
    float q = fmaf(x2, fmaf(x2, fmaf(x2, 28.0f, 3150.0f), 62370.0f), 135135.0f);
    return p * __builtin_amdgcn_rcpf(q);
}
// branchless gate activation: sigma(z) = 0.5 + 0.5*tanh(z/2); tanh direct
__device__ __forceinline__ float act(float z, bool istanh) {
    float zin = istanh ? z : 0.5f * z;
    float t = tanh_rat(zin);
    return istanh ? t : fmaf(0.5f, t, 0.5f);
}
__device__ __forceinline__ float sigmf(float v) { return 1.0f / (1.0f + __expf(-v)); }

// LDS-only barrier (R13-validated): __syncthreads() emits s_waitcnt vmcnt(0)
// lgkmcnt(0) + s_barrier, force-draining the in-flight global x-prefetch every
// step. The h-exchange only needs LDS ordering -> wait lgkmcnt(0) only; global
// loads are waited by the compiler at their consumption point.
#define LDS_BARRIER() asm volatile("s_waitcnt lgkmcnt(0)\n\ts_barrier" ::: "memory")

// One block per batch row; 512 threads = 8 waves (R8 structure -- best of 8
// structures tried: lockstep 2/8/16-wave, 1-wave, 2-row, MFMA, async rings all
// land 1900-2400 cyc/step; the floor is the intra-step latency chain).
// Waves 0-3: layer-1 engine (one step ahead). Waves 4-7: layer-2 + projection.
// Thread map: unit u = wid*16 + (l&15), K-quarter kq = l>>4. Each thread owns
// all 4 gates of its unit over its K-chunk (v_pk_fma_f16), combine = 3
// shfl_xor, gather = 3 shfl_xor, cell update in kq0 roles. 1 barrier/step.
__global__ __launch_bounds__(512, 2)
void dlstm_kernel(const float* __restrict__ x,
                  const float* __restrict__ W1, const float* __restrict__ U1,
                  const float* __restrict__ b1,
                  const float* __restrict__ W2, const float* __restrict__ U2,
                  const float* __restrict__ b2,
                  const float* __restrict__ Wd, const float* __restrict__ bd,
                  float* __restrict__ out)
{
    const int tid = threadIdx.x, b = blockIdx.x;
    const int wid = tid >> 6, l = tid & 63;
    const int kq = l >> 4, ul = l & 15;
    const bool istanh = (kq == 2);

    __shared__ __align__(16) __half h1b[2][HH];
    __shared__ __align__(16) __half h2b[2][HH];
    __shared__ float pbuf[2][4];

    if (tid < HH) {
        h1b[0][tid] = __float2half(0.f); h1b[1][tid] = __float2half(0.f);
        h2b[0][tid] = __float2half(0.f); h2b[1][tid] = __float2half(0.f);
    }
    if (tid < 8) pbuf[tid >> 2][tid & 3] = 0.f;
    __syncthreads();

    if (wid < 4) {
        // ================= layer-1 engine: computes h1(n) at iter n =================
        const int u = (wid << 4) + ul;
        __half2 u1p[4][8];
        #pragma unroll
        for (int gp = 0; gp < 4; ++gp)
            #pragma unroll
            for (int j = 0; j < 8; ++j)
                u1p[gp][j] = __floats2half2_rn(U1[(kq*16 + 2*j    ) * GG + gp*HH + u],
                                               U1[(kq*16 + 2*j + 1) * GG + gp*HH + u]);
        __half2 w1p[4][4];
        #pragma unroll
        for (int gp = 0; gp < 4; ++gp)
            #pragma unroll
            for (int j = 0; j < 4; ++j)
                w1p[gp][j] = __floats2half2_rn(W1[(kq*8 + 2*j    ) * GG + gp*HH + u],
                                               W1[(kq*8 + 2*j + 1) * GG + gp*HH + u]);
        const float b1k = b1[kq * HH + u];
        const float bd0 = bd[0];
        float c1 = 0.f;

        const float* xr = x + (size_t)b * TT * DD + kq * 8;   // my 8 x-elems
        float4 xa = *(const float4*)(xr);
        float4 xb = *(const float4*)(xr + 4);

        for (int n = 0; n < TT + 2; ++n) {
            const int p = n & 1;
            if (n < TT) {
                const size_t tn = (n + 1 < TT) ? (size_t)(n + 1) : (size_t)n;
                float4 na = *(const float4*)(xr + tn * DD);   // prefetch x(n+1):
                float4 nb = *(const float4*)(xr + tn * DD + 4); // stays in flight (no vmcnt drain)

                __half2 xx[4];
                xx[0] = __floats2half2_rn(xa.x, xa.y);
                xx[1] = __floats2half2_rn(xa.z, xa.w);
                xx[2] = __floats2half2_rn(xb.x, xb.y);
                xx[3] = __floats2half2_rn(xb.z, xb.w);

                const __half2* hp = (const __half2*)&h1b[p][kq * 16];
                __half2 hh[8];
                #pragma unroll
                for (int j = 0; j < 8; ++j) hh[j] = hp[j];

                float ag[4];
                #pragma unroll
                for (int gp = 0; gp < 4; ++gp) {
                    __half2 s = __float2half2_rn(0.f);
                    #pragma unroll
                    for (int j = 0; j < 8; ++j) s = __hfma2(u1p[gp][j], hh[j], s);
                    #pragma unroll
                    for (int j = 0; j < 4; ++j) s = __hfma2(w1p[gp][j], xx[j], s);
                    ag[gp] = __low2float(s) + __high2float(s);
                }
                // combine across kq: lane ends with z-total of gate kq (R5/R8-verified)
                float t1 = (kq & 1) ? ag[0] : ag[1];
                float t2 = (kq & 1) ? ag[2] : ag[3];
                float r1 = __shfl_xor(t1, 16, 64);
                float r2 = __shfl_xor(t2, 16, 64);
                float m1 = (kq & 1) ? ag[1] : ag[0];
                float m2 = (kq & 1) ? ag[3] : ag[2];
                float s1 = m1 + r1, s2 = m2 + r2;
                float t3 = (kq < 2) ? s2 : s1;
                float r3 = __shfl_xor(t3, 32, 64);
                float mine = (kq < 2) ? s1 : s2;
                float z = mine + r3 + b1k;

                float a = act(z, istanh);
                float g16 = __shfl_xor(a, 16, 64);
                float g32 = __shfl_xor(a, 32, 64);
                float g48 = __shfl_xor(g16, 32, 64);
                c1 = g16 * c1 + a * g32;         // kq0 roles: i=a f=g16 c~=g32 o=g48
                float h = g48 * tanh_rat(c1);
                if (kq == 0) h1b[p ^ 1][u] = __float2half(h);

                xa = na; xb = nb;
            }
            // out(n-2): partials written by L2 at iter n-1
            if (tid == 0 && n >= 2) {
                float s = pbuf[p][0] + pbuf[p][1] + pbuf[p][2] + pbuf[p][3];
                out[(size_t)b * TT + (n - 2)] = sigmf(s + bd0);
            }
            LDS_BARRIER();
        }
    } else {
        // ================= layer-2 engine: computes h2(n-1) at iter n =================
        const int w2i = wid - 4;
        const int u = (w2i << 4) + ul;
        __half2 w2p[4][8], u2p[4][8];
        #pragma unroll
        for (int gp = 0; gp < 4; ++gp)
            #pragma unroll
            for (int j = 0; j < 8; ++j) {
                w2p[gp][j] = __floats2half2_rn(W2[(kq*16 + 2*j    ) * GG + gp*HH + u],
                                               W2[(kq*16 + 2*j + 1) * GG + gp*HH + u]);
                u2p[gp][j] = __floats2half2_rn(U2[(kq*16 + 2*j    ) * GG + gp*HH + u],
                                               U2[(kq*16 + 2*j + 1) * GG + gp*HH + u]);
            }
        const float b2k = b2[kq * HH + u];
        const float wdu = Wd[u];
        float c2 = 0.f;

        for (int n = 0; n < TT + 2; ++n) {
            const int p = n & 1;
            if (n >= 1 && n <= TT) {
                const __half2* h1p = (const __half2*)&h1b[p][kq * 16];
                const __half2* h2p = (const __half2*)&h2b[p][kq * 16];
                __half2 hh1[8], hh2[8];
                #pragma unroll
                for (int j = 0; j < 8; ++j) { hh1[j] = h1p[j]; hh2[j] = h2p[j]; }

                float ag[4];
                #pragma unroll
                for (int gp = 0; gp < 4; ++gp) {
                    __half2 s = __float2half2_rn(0.f);
                    #pragma unroll
                    for (int j = 0; j < 8; ++j) s = __hfma2(w2p[gp][j], hh1[j], s);
                    #pragma unroll
                    for (int j = 0; j < 8; ++j) s = __hfma2(u2p[gp][j], hh2[j], s);
                    ag[gp] = __low2float(s) + __high2float(s);
                }
                float t1 = (kq & 1) ? ag[0] : ag[1];
                float t2 = (kq & 1) ? ag[2] : ag[3];
                float r1 = __shfl_xor(t1, 16, 64);
                float r2 = __shfl_xor(t2, 16, 64);
                float m1 = (kq & 1) ? ag[1] : ag[0];
                float m2 = (kq & 1) ? ag[3] : ag[2];
                float s1 = m1 + r1, s2 = m2 + r2;
                float t3 = (kq < 2) ? s2 : s1;
                float r3 = __shfl_xor(t3, 32, 64);
                float mine = (kq < 2) ? s1 : s2;
                float z = mine + r3 + b2k;

                float a = act(z, istanh);
                float g16 = __shfl_xor(a, 16, 64);
                float g32 = __shfl_xor(a, 32, 64);
                float g48 = __shfl_xor(g16, 32, 64);
                c2 = g16 * c2 + a * g32;         // kq0 roles
                float h = g48 * tanh_rat(c2);
                if (kq == 0) h2b[p ^ 1][u] = __float2half(h);

                // projection partial: only kq0 lanes contribute real h
                float v = (kq == 0) ? h * wdu : 0.f;
                v += __shfl_xor(v, 1, 64);
                v += __shfl_xor(v, 2, 64);
                v += __shfl_xor(v, 4, 64);
                v += __shfl_xor(v, 8, 64);
                if (l == 0) pbuf[p ^ 1][w2i] = v;
            }
            LDS_BARRIER();
        }
    }
}

extern "C" void kernel_launch(void* const* d_in, const int* in_sizes, int n_in,
                              void* d_out, int out_size, void* d_ws, size_t ws_size,
                              hipStream_t stream) {
    const float* x  = (const float*)d_in[0];
    const float* W1 = (const float*)d_in[1];
    const float* U1 = (const float*)d_in[2];
    const float* b1 = (const float*)d_in[3];
    const float* W2 = (const float*)d_in[4];
    const float* U2 = (const float*)d_in[5];
    const float* b2 = (const float*)d_in[6];
    const float* Wd = (const float*)d_in[7];
    const float* bd = (const float*)d_in[8];
    float* out = (float*)d_out;

    dlstm_kernel<<<dim3(BB), dim3(512), 0, stream>>>(
        x, W1, U1, b1, W2, U2, b2, Wd, bd, out);
}